// Round 1
// baseline (509.845 us; speedup 1.0000x reference)
//
#include <hip/hip_runtime.h>

#define GN 512  // N hard-coded per reference

// g[b,i,j] = cos(phi_i + phi_j) = c_i*c_j - s_i*s_j
// c = clamp(minmax_scale(x), -1+eps, 1-eps), s = sqrt(1-c^2)  (phi in [0,pi])
//
// Restructure vs previous version: column (c,s) fragments live in REGISTERS
// (loaded from LDS once per block); each wave emits one full 2 KB row per
// iteration with two coalesced dwordx4 stores. Per-row LDS traffic is just
// two broadcast b32 reads, so store issue is no longer throttled by the
// ds_read -> lgkmcnt -> VALU dependent chain.
__global__ __launch_bounds__(256, 8) void gram_kernel(const float* __restrict__ x,
                                                      float* __restrict__ out) {
    __shared__ float sc[GN];
    __shared__ float ss[GN];
    __shared__ float wmin[4], wmax[4];

    const int b    = blockIdx.x;   // batch
    const int part = blockIdx.y;   // 0..3 -> rows [part*128, part*128+128)
    const int t    = threadIdx.x;  // 0..255
    const int lane = t & 63;
    const int wave = t >> 6;

    // ---- Phase 1: per-batch min/max + c,s into LDS (2 elems per thread) ----
    const float* xb = x + (size_t)b * GN;
    float2 v = ((const float2*)xb)[t];

    float lmin = fminf(v.x, v.y);
    float lmax = fmaxf(v.x, v.y);
    #pragma unroll
    for (int off = 32; off > 0; off >>= 1) {
        lmin = fminf(lmin, __shfl_down(lmin, off));
        lmax = fmaxf(lmax, __shfl_down(lmax, off));
    }
    if (lane == 0) { wmin[wave] = lmin; wmax[wave] = lmax; }
    __syncthreads();
    const float mn  = fminf(fminf(wmin[0], wmin[1]), fminf(wmin[2], wmin[3]));
    const float mx  = fmaxf(fmaxf(wmax[0], wmax[1]), fmaxf(wmax[2], wmax[3]));
    const float inv = 1.0f / (mx - mn);
    const float eps = 1e-6f;
    const float lo  = -1.0f + eps, hi = 1.0f - eps;

    float c0 = fminf(fmaxf((2.0f * v.x - mx - mn) * inv, lo), hi);
    float c1 = fminf(fmaxf((2.0f * v.y - mx - mn) * inv, lo), hi);
    sc[2 * t]     = c0;
    sc[2 * t + 1] = c1;
    ss[2 * t]     = sqrtf(fmaxf(1.0f - c0 * c0, 0.0f));
    ss[2 * t + 1] = sqrtf(fmaxf(1.0f - c1 * c1, 0.0f));
    __syncthreads();

    // ---- Phase 2: column fragments -> registers (once), then row stream ----
    // Lane owns columns [j0, j0+4) and [256+j0, 256+j0+4).
    const int j0 = lane << 2;
    const float4 cj0 = *(const float4*)&sc[j0];
    const float4 sj0 = *(const float4*)&ss[j0];
    const float4 cj1 = *(const float4*)&sc[256 + j0];
    const float4 sj1 = *(const float4*)&ss[256 + j0];

    // Wave handles 32 consecutive rows; writes each full 512-float row as
    // two contiguous 1 KB wave-stores (both dwordx4, fully coalesced).
    const int r0 = part * 128 + wave * 32;
    float* rowp = out + (size_t)b * GN * GN + (size_t)r0 * GN;

    #pragma unroll 2
    for (int rr = 0; rr < 32; ++rr) {
        const float ci = sc[r0 + rr];  // LDS broadcast (lane-uniform addr)
        const float si = ss[r0 + rr];

        float4 g0, g1;
        g0.x = fmaf(ci, cj0.x, -si * sj0.x);
        g0.y = fmaf(ci, cj0.y, -si * sj0.y);
        g0.z = fmaf(ci, cj0.z, -si * sj0.z);
        g0.w = fmaf(ci, cj0.w, -si * sj0.w);
        g1.x = fmaf(ci, cj1.x, -si * sj1.x);
        g1.y = fmaf(ci, cj1.y, -si * sj1.y);
        g1.z = fmaf(ci, cj1.z, -si * sj1.z);
        g1.w = fmaf(ci, cj1.w, -si * sj1.w);

        *(float4*)(rowp + j0)       = g0;  // cols [0,256)   of row
        *(float4*)(rowp + 256 + j0) = g1;  // cols [256,512) of row
        rowp += GN;
    }
}

extern "C" void kernel_launch(void* const* d_in, const int* in_sizes, int n_in,
                              void* d_out, int out_size, void* d_ws, size_t ws_size,
                              hipStream_t stream) {
    const float* x = (const float*)d_in[0];
    float* out = (float*)d_out;
    dim3 grid(512, 4);  // 512 batches x 4 row-quarters = 2048 blocks (8/CU)
    gram_kernel<<<grid, 256, 0, stream>>>(x, out);
}